// Round 4
// baseline (1050.425 us; speedup 1.0000x reference)
//
#include <hip/hip_runtime.h>
#include <math.h>

#define N_NODES 4096
#define DIM 384
#define QKVD 1152
#define N_EDGES 131072
#define N_HEADS 8
#define DH 48
#define N_LAYERS 3

typedef short v4s __attribute__((ext_vector_type(4)));
typedef short v8s __attribute__((ext_vector_type(8)));
typedef float v4f __attribute__((ext_vector_type(4)));

#define MFMA32(A, B, C) __builtin_amdgcn_mfma_f32_16x16x32_bf16(A, B, C, 0, 0, 0)
#define MFMA16(A, B, C) __builtin_amdgcn_mfma_f32_16x16x16bf16_1k(A, B, C, 0, 0, 0)
#define EXP2F(x) __builtin_exp2f(x)

// ======================= CSR build (counting sort by dst) =======================

__global__ void zero_counts_kernel(int* counts, int* cursor) {
  int i = blockIdx.x * blockDim.x + threadIdx.x;
  if (i < N_NODES) { counts[i] = 0; cursor[i] = 0; }
}

__global__ void count_kernel(const int* __restrict__ dst, int* counts) {
  int e = blockIdx.x * blockDim.x + threadIdx.x;
  if (e < N_EDGES) atomicAdd(&counts[dst[e]], 1);
}

__global__ __launch_bounds__(1024) void scan_kernel(const int* __restrict__ counts,
                                                    int* __restrict__ offsets) {
  __shared__ int s[1024];
  int t = threadIdx.x;
  int base = t * 4;
  int c[4];
  int sum = 0;
  #pragma unroll
  for (int i = 0; i < 4; i++) { c[i] = counts[base + i]; sum += c[i]; }
  s[t] = sum;
  __syncthreads();
  for (int off = 1; off < 1024; off <<= 1) {
    int v = (t >= off) ? s[t - off] : 0;
    __syncthreads();
    s[t] += v;
    __syncthreads();
  }
  int excl = s[t] - sum;
  #pragma unroll
  for (int i = 0; i < 4; i++) { offsets[base + i] = excl; excl += c[i]; }
  if (t == 1023) offsets[N_NODES] = s[1023];
}

__global__ void scatter_kernel(const int* __restrict__ dst, const int* __restrict__ src,
                               const int* __restrict__ offsets, int* cursor,
                               int* __restrict__ ssrc) {
  int e = blockIdx.x * blockDim.x + threadIdx.x;
  if (e < N_EDGES) {
    int d = dst[e];
    int pos = atomicAdd(&cursor[d], 1);
    ssrc[offsets[d] + pos] = src[e];
  }
}

// ======================= bf16 split helpers =======================

__device__ __forceinline__ void bsplit(float v, ushort& hi, ushort& lo) {
  unsigned b = __float_as_uint(v);
  unsigned hb = b & 0xFFFF0000u;
  hi = (ushort)(b >> 16);
  float r = v - __uint_as_float(hb);
  lo = (ushort)(__float_as_uint(r) >> 16);
}

__device__ __forceinline__ void psplit2(float a, float b, unsigned& hi, unsigned& lo) {
  hi = __builtin_amdgcn_perm(__float_as_uint(b), __float_as_uint(a), 0x07060302u);
  float ra = a - __uint_as_float(hi << 16);
  float rb = b - __uint_as_float(hi & 0xFFFF0000u);
  lo = __builtin_amdgcn_perm(__float_as_uint(rb), __float_as_uint(ra), 0x07060302u);
}

// ======================= neighbor aggregation (+ split epilogue) =================

__global__ __launch_bounds__(128) void aggregate_kernel(const float* __restrict__ h,
    const int* __restrict__ ssrc, const int* __restrict__ offsets,
    ushort* __restrict__ aggH, ushort* __restrict__ aggL) {
  int i = blockIdx.x;
  int t = threadIdx.x;
  int e0 = offsets[i], e1 = offsets[i + 1];
  float a0 = 0.f, a1 = 0.f, a2 = 0.f;
  for (int e = e0; e < e1; e++) {
    const float* row = h + (size_t)ssrc[e] * DIM;
    a0 += row[t];
    a1 += row[t + 128];
    a2 += row[t + 256];
  }
  ushort h0, l0, h1, l1, h2, l2;
  bsplit(a0, h0, l0); bsplit(a1, h1, l1); bsplit(a2, h2, l2);
  size_t base = (size_t)i * DIM;
  aggH[base + t] = h0;       aggL[base + t] = l0;
  aggH[base + t + 128] = h1; aggL[base + t + 128] = l1;
  aggH[base + t + 256] = h2; aggL[base + t + 256] = l2;
}

// ======================= weight prep kernels =======================

// transpose Wc[l] (384x384) -> Wct[l][j][k] = Wc[l][k][j], split hi/lo
__global__ void transpose_split_kernel(const float* __restrict__ Wc,
    ushort* __restrict__ wctH, ushort* __restrict__ wctL) {
  __shared__ float s[32][33];
  const int l = blockIdx.z;
  const float* W = Wc + (size_t)l * DIM * DIM;
  int tx = threadIdx.x, ty = threadIdx.y;
  s[ty][tx] = W[(size_t)(blockIdx.y * 32 + ty) * DIM + blockIdx.x * 32 + tx];
  __syncthreads();
  float v = s[tx][ty];
  ushort hi, lo;
  bsplit(v, hi, lo);
  size_t off = (size_t)l * DIM * DIM + (size_t)(blockIdx.x * 32 + ty) * DIM + blockIdx.y * 32 + tx;
  wctH[off] = hi;
  wctL[off] = lo;
}

// elementwise fp32 -> hi/lo split
__global__ void split_kernel(const float* __restrict__ src,
    ushort* __restrict__ hi, ushort* __restrict__ lo, int n) {
  int i = (blockIdx.x * 256 + threadIdx.x) * 4;
  if (i >= n) return;
  float4 v = *(const float4*)(src + i);
  ushort4 H, L;
  bsplit(v.x, H.x, L.x); bsplit(v.y, H.y, L.y);
  bsplit(v.z, H.z, L.z); bsplit(v.w, H.w, L.w);
  *(ushort4*)(hi + i) = H;
  *(ushort4*)(lo + i) = L;
}

// wibc[l][i] = dot(Wi[i,:], b_conv[l,:])
__global__ __launch_bounds__(256) void wibc_kernel(const float* __restrict__ Wi,
    const float* __restrict__ bconv, float* __restrict__ wibc) {
  int gw = (blockIdx.x * 256 + threadIdx.x) >> 6;
  int lane = threadIdx.x & 63;
  if (gw >= 3 * QKVD) return;
  int l = gw / QKVD, i = gw - l * QKVD;
  const float* w = Wi + (size_t)i * DIM;
  const float* b = bconv + (size_t)l * DIM;
  float s = 0.f;
  #pragma unroll
  for (int c = 0; c < 6; c++) s += w[lane + c * 64] * b[lane + c * 64];
  #pragma unroll
  for (int off = 32; off >= 1; off >>= 1) s += __shfl_xor(s, off, 64);
  if (lane == 0) wibc[gw] = s;
}

// ======================= split-bf16 MFMA GEMM core ==============================
// D[mBase+mt*16+quad*4+r][nBase+nt*16+li] = sum_k A[arow,k]*B[brow,k], 3-term emu.
// A,B row-major [rows][K] hi/lo ushort; loads direct from global (L1/L2 reuse).

template<int K>
__device__ __forceinline__ void mfma_core(
    const ushort* __restrict__ Ah, const ushort* __restrict__ Al,
    const ushort* __restrict__ Bh, const ushort* __restrict__ Bl,
    int aRow0, int bRow0, int li, int quad, v4f acc[4][4])
{
  for (int k0 = 0; k0 < K; k0 += 32) {
    v8s Afh[4], Afl[4], Bfh[4], Bfl[4];
    #pragma unroll
    for (int t = 0; t < 4; t++) {
      size_t ao = (size_t)(aRow0 + t * 16 + li) * K + k0 + quad * 8;
      size_t bo = (size_t)(bRow0 + t * 16 + li) * K + k0 + quad * 8;
      Afh[t] = *(const v8s*)(Ah + ao);
      Afl[t] = *(const v8s*)(Al + ao);
      Bfh[t] = *(const v8s*)(Bh + bo);
      Bfl[t] = *(const v8s*)(Bl + bo);
    }
    #pragma unroll
    for (int mt = 0; mt < 4; mt++)
      #pragma unroll
      for (int nt = 0; nt < 4; nt++) {
        v4f a = acc[mt][nt];
        a = MFMA32(Afh[mt], Bfh[nt], a);
        a = MFMA32(Afl[mt], Bfh[nt], a);
        a = MFMA32(Afh[mt], Bfl[nt], a);
        acc[mt][nt] = a;
      }
  }
}

// --- weight-prep GEMM: Wf[l] = Wi @ Wct[l]  (M=1152, N=384), split output ---
__global__ __launch_bounds__(256) void wprep_gemm(
    const ushort* __restrict__ wiH, const ushort* __restrict__ wiL,
    const ushort* __restrict__ wctH, const ushort* __restrict__ wctL,
    ushort* __restrict__ wfH, ushort* __restrict__ wfL)
{
  const int l = blockIdx.z;
  const ushort* Bh = wctH + (size_t)l * DIM * DIM;
  const ushort* Bl = wctL + (size_t)l * DIM * DIM;
  ushort* oH = wfH + (size_t)l * QKVD * DIM;
  ushort* oL = wfL + (size_t)l * QKVD * DIM;
  const int tid = threadIdx.x;
  const int lane = tid & 63, li = lane & 15, quad = lane >> 4;
  const int w = tid >> 6, wm = w & 1, wn = w >> 1;
  const int aRow0 = blockIdx.x * 128 + wm * 64;
  const int bRow0 = blockIdx.y * 128 + wn * 64;
  v4f acc[4][4] = {};
  mfma_core<DIM>(wiH, wiL, Bh, Bl, aRow0, bRow0, li, quad, acc);
  #pragma unroll
  for (int mt = 0; mt < 4; mt++) {
    int i0 = aRow0 + mt * 16 + quad * 4;
    #pragma unroll
    for (int nt = 0; nt < 4; nt++) {
      int j = bRow0 + nt * 16 + li;
      #pragma unroll
      for (int r = 0; r < 4; r++) {
        ushort hi, lo;
        bsplit(acc[mt][nt][r], hi, lo);
        oH[(size_t)(i0 + r) * DIM + j] = hi;
        oL[(size_t)(i0 + r) * DIM + j] = lo;
      }
    }
  }
}

// --- fused qkv GEMM: out[c][node] = Wf[c,:]·agg[node,:] + deg[node]*wibc[c] + b_in[c]
//     M-side = channels (1152), N-side = nodes (4096). q scaled, routed to layouts.
__global__ __launch_bounds__(256) void qkv_gemm(
    const ushort* __restrict__ wfH, const ushort* __restrict__ wfL,
    const ushort* __restrict__ aggH, const ushort* __restrict__ aggL,
    const float* __restrict__ wibc_l, const float* __restrict__ b_in,
    const int* __restrict__ deg,
    ushort* __restrict__ qhi, ushort* __restrict__ qlo,
    ushort* __restrict__ khi, ushort* __restrict__ klo,
    ushort* __restrict__ vthi, ushort* __restrict__ vtlo)
{
  const int tid = threadIdx.x;
  const int lane = tid & 63, li = lane & 15, quad = lane >> 4;
  const int w = tid >> 6, wm = w & 1, wn = w >> 1;
  const int aRow0 = blockIdx.x * 128 + wm * 64;   // channel base
  const int bRow0 = blockIdx.y * 128 + wn * 64;   // node base
  v4f acc[4][4] = {};
  mfma_core<DIM>(wfH, wfL, aggH, aggL, aRow0, bRow0, li, quad, acc);

  const float cq = 0.20823507f;  // log2(e)/sqrt(48)
  int node[4]; float degf[4];
  #pragma unroll
  for (int nt = 0; nt < 4; nt++) {
    node[nt] = bRow0 + nt * 16 + li;
    degf[nt] = (float)deg[node[nt]];
  }
  #pragma unroll
  for (int mt = 0; mt < 4; mt++) {
    const int c0 = aRow0 + mt * 16 + quad * 4;
    const int part = c0 / DIM;
    const int cm = c0 - part * DIM;
    const int hd = cm / DH;
    const int d0 = cm - hd * DH;
    float wb[4], bb[4];
    #pragma unroll
    for (int r = 0; r < 4; r++) { wb[r] = wibc_l[c0 + r]; bb[r] = b_in[c0 + r]; }
    #pragma unroll
    for (int nt = 0; nt < 4; nt++) {
      float v0 = acc[mt][nt][0] + degf[nt] * wb[0] + bb[0];
      float v1 = acc[mt][nt][1] + degf[nt] * wb[1] + bb[1];
      float v2 = acc[mt][nt][2] + degf[nt] * wb[2] + bb[2];
      float v3 = acc[mt][nt][3] + degf[nt] * wb[3] + bb[3];
      if (part == 0) {
        v0 *= cq; v1 *= cq; v2 *= cq; v3 *= cq;
        ushort4 H, L;
        bsplit(v0, H.x, L.x); bsplit(v1, H.y, L.y);
        bsplit(v2, H.z, L.z); bsplit(v3, H.w, L.w);
        size_t off = ((size_t)hd * N_NODES + node[nt]) * DH + d0;
        *(ushort4*)(qhi + off) = H;
        *(ushort4*)(qlo + off) = L;
      } else if (part == 1) {
        ushort4 H, L;
        bsplit(v0, H.x, L.x); bsplit(v1, H.y, L.y);
        bsplit(v2, H.z, L.z); bsplit(v3, H.w, L.w);
        size_t off = ((size_t)hd * N_NODES + node[nt]) * DH + d0;
        *(ushort4*)(khi + off) = H;
        *(ushort4*)(klo + off) = L;
      } else {
        float vv[4] = {v0, v1, v2, v3};
        #pragma unroll
        for (int r = 0; r < 4; r++) {
          ushort hi, lo;
          bsplit(vv[r], hi, lo);
          size_t off = ((size_t)hd * DH + d0 + r) * N_NODES + node[nt];
          vthi[off] = hi;
          vtlo[off] = lo;
        }
      }
    }
  }
}

// --- attn-out GEMM: h[m][n] = relu(ao[m,:]·Wao[n,:] + b_ao[n] + h[m][n]) ---
__global__ __launch_bounds__(256) void outproj_gemm(
    const ushort* __restrict__ aoH, const ushort* __restrict__ aoL,
    const ushort* __restrict__ waoH, const ushort* __restrict__ waoL,
    const float* __restrict__ b_ao, float* __restrict__ h)
{
  const int tid = threadIdx.x;
  const int lane = tid & 63, li = lane & 15, quad = lane >> 4;
  const int w = tid >> 6, wm = w & 1, wn = w >> 1;
  const int aRow0 = blockIdx.x * 128 + wm * 64;   // node base
  const int bRow0 = blockIdx.y * 128 + wn * 64;   // channel base
  v4f acc[4][4] = {};
  mfma_core<DIM>(aoH, aoL, waoH, waoL, aRow0, bRow0, li, quad, acc);
  #pragma unroll
  for (int mt = 0; mt < 4; mt++) {
    int m0 = aRow0 + mt * 16 + quad * 4;
    #pragma unroll
    for (int nt = 0; nt < 4; nt++) {
      int n = bRow0 + nt * 16 + li;
      float ba = b_ao[n];
      #pragma unroll
      for (int r = 0; r < 4; r++) {
        size_t off = (size_t)(m0 + r) * DIM + n;
        float v = acc[mt][nt][r] + ba + h[off];
        h[off] = fmaxf(v, 0.f);
      }
    }
  }
}

// ======================= MFMA flash attention (split-bf16) ======================
// grid (H=8, N/32=128), 256 thr = 4 waves. Wave w owns kcol slice [kb+16w, ...+16).
// 32 Q-rows per block (2 q-tiles). No LDS/barrier in K-loop; 4-way merge at end.

__global__ __launch_bounds__(256, 3) void attn_kernel(
    const ushort* __restrict__ qhi, const ushort* __restrict__ qlo,
    const ushort* __restrict__ khi, const ushort* __restrict__ klo,
    const ushort* __restrict__ vthi, const ushort* __restrict__ vtlo,
    ushort* __restrict__ aoH, ushort* __restrict__ aoL)
{
  const int head = blockIdx.x;
  const int qBase = blockIdx.y * 32;
  const int tid = threadIdx.x;
  const int w = tid >> 6;
  const int lane = tid & 63;
  const int li = lane & 15, quad = lane >> 4;

  const size_t headQK = (size_t)head * N_NODES * DH;
  const size_t headV  = (size_t)head * DH * N_NODES;

  // resident Q fragments (2 q-tiles of 16 rows)
  v8s q0h[2], q0l[2];
  v4s q1h[2], q1l[2];
  #pragma unroll
  for (int qt = 0; qt < 2; qt++) {
    const ushort* qr = qhi + headQK + (size_t)(qBase + 16 * qt + li) * DH;
    const ushort* ql = qlo + headQK + (size_t)(qBase + 16 * qt + li) * DH;
    q0h[qt] = *(const v8s*)(qr + quad * 8);
    q0l[qt] = *(const v8s*)(ql + quad * 8);
    q1h[qt] = *(const v4s*)(qr + 32 + quad * 4);
    q1l[qt] = *(const v4s*)(ql + 32 + quad * 4);
  }

  v4f ot[3][2];
  #pragma unroll
  for (int mt = 0; mt < 3; mt++)
    #pragma unroll
    for (int qt = 0; qt < 2; qt++)
      ot[mt][qt] = (v4f){0.f, 0.f, 0.f, 0.f};
  float m2[2] = {-3.0e38f, -3.0e38f};
  float lsum[2] = {0.f, 0.f};

  const ushort* kh_p = khi + headQK + (size_t)(16 * w + li) * DH;
  const ushort* kl_p = klo + headQK + (size_t)(16 * w + li) * DH;
  const ushort* vh_p = vthi + headV + (size_t)li * N_NODES + 16 * w + quad * 4;
  const ushort* vl_p = vtlo + headV + (size_t)li * N_NODES + 16 * w + quad * 4;

  v8s nk0h = *(const v8s*)(kh_p + quad * 8);
  v8s nk0l = *(const v8s*)(kl_p + quad * 8);
  v4s nk1h = *(const v4s*)(kh_p + 32 + quad * 4);
  v4s nk1l = *(const v4s*)(kl_p + 32 + quad * 4);
  v4s nvh[3], nvl[3];
  #pragma unroll
  for (int mt = 0; mt < 3; mt++) {
    nvh[mt] = *(const v4s*)(vh_p + (size_t)mt * 16 * N_NODES);
    nvl[mt] = *(const v4s*)(vl_p + (size_t)mt * 16 * N_NODES);
  }

  for (int kb = 0; kb < N_NODES; kb += 64) {
    v8s ck0h = nk0h, ck0l = nk0l;
    v4s ck1h = nk1h, ck1l = nk1l;
    v4s cvh[3], cvl[3];
    #pragma unroll
    for (int mt = 0; mt < 3; mt++) { cvh[mt] = nvh[mt]; cvl[mt] = nvl[mt]; }

    if (kb + 64 < N_NODES) {
      kh_p += 64 * DH; kl_p += 64 * DH; vh_p += 64; vl_p += 64;
      nk0h = *(const v8s*)(kh_p + quad * 8);
      nk0l = *(const v8s*)(kl_p + quad * 8);
      nk1h = *(const v4s*)(kh_p + 32 + quad * 4);
      nk1l = *(const v4s*)(kl_p + 32 + quad * 4);
      #pragma unroll
      for (int mt = 0; mt < 3; mt++) {
        nvh[mt] = *(const v4s*)(vh_p + (size_t)mt * 16 * N_NODES);
        nvl[mt] = *(const v4s*)(vl_p + (size_t)mt * 16 * N_NODES);
      }
    }

    // S^T = K·Q^T (log2-domain scores via pre-scaled q)
    v4f s[2];
    #pragma unroll
    for (int qt = 0; qt < 2; qt++) {
      v4f acc = (v4f){0.f, 0.f, 0.f, 0.f};
      acc = MFMA32(ck0h, q0h[qt], acc);
      acc = MFMA32(ck0l, q0h[qt], acc);
      acc = MFMA32(ck0h, q0l[qt], acc);
      acc = MFMA16(ck1h, q1h[qt], acc);
      acc = MFMA16(ck1l, q1h[qt], acc);
      acc = MFMA16(ck1h, q1l[qt], acc);
      s[qt] = acc;
    }

    // online softmax over this wave's 16 kcols
    v4s pH[2], pL[2];
    float al[2];
    #pragma unroll
    for (int qt = 0; qt < 2; qt++) {
      float mx = fmaxf(fmaxf(s[qt][0], s[qt][1]), fmaxf(s[qt][2], s[qt][3]));
      mx = fmaxf(mx, __shfl_xor(mx, 16, 64));
      mx = fmaxf(mx, __shfl_xor(mx, 32, 64));
      float mn = fmaxf(m2[qt], mx);
      float a = EXP2F(m2[qt] - mn);
      m2[qt] = mn;
      al[qt] = a;
      float p0 = EXP2F(s[qt][0] - mn);
      float p1 = EXP2F(s[qt][1] - mn);
      float p2 = EXP2F(s[qt][2] - mn);
      float p3 = EXP2F(s[qt][3] - mn);
      float rs = (p0 + p1) + (p2 + p3);
      rs += __shfl_xor(rs, 16, 64);
      rs += __shfl_xor(rs, 32, 64);
      lsum[qt] = lsum[qt] * a + rs;
      unsigned h0, l0, h1, l1;
      psplit2(p0, p1, h0, l0);
      psplit2(p2, p3, h1, l1);
      union { uint2 u; v4s v; } uh, ul;
      uh.u = make_uint2(h0, h1);
      ul.u = make_uint2(l0, l1);
      pH[qt] = uh.v;
      pL[qt] = ul.v;
    }

    bool resc = (al[0] != 1.f) | (al[1] != 1.f);
    if (__any(resc)) {
      #pragma unroll
      for (int mt = 0; mt < 3; mt++)
        #pragma unroll
        for (int qt = 0; qt < 2; qt++)
          ot[mt][qt] *= al[qt];
    }

    // O^T += V^T · P^T
    #pragma unroll
    for (int mt = 0; mt < 3; mt++) {
      #pragma unroll
      for (int qt = 0; qt < 2; qt++) {
        v4f acc = ot[mt][qt];
        acc = MFMA16(cvh[mt], pH[qt], acc);
        acc = MFMA16(cvl[mt], pH[qt], acc);
        acc = MFMA16(cvh[mt], pL[qt], acc);
        ot[mt][qt] = acc;
      }
    }
  }

  // merge the 4 per-wave partials
  __shared__ float Obuf[4][32][49];
  __shared__ float Mbuf[4][2][16];
  __shared__ float Lbuf[4][2][16];

  #pragma unroll
  for (int mt = 0; mt < 3; mt++)
    #pragma unroll
    for (int qt = 0; qt < 2; qt++)
      #pragma unroll
      for (int r = 0; r < 4; r++)
        Obuf[w][16 * qt + li][16 * mt + 4 * quad + r] = ot[mt][qt][r];
  if (quad == 0) {
    #pragma unroll
    for (int qt = 0; qt < 2; qt++) {
      Mbuf[w][qt][li] = m2[qt];
      Lbuf[w][qt][li] = lsum[qt];
    }
  }
  __syncthreads();

  // wave w outputs rows [8w, 8w+8); each lane: 1 row, 6 cols
  int orow = 8 * w + (lane >> 3);
  int c0 = (lane & 7) * 6;
  int rq = orow >> 4, rl = orow & 15;
  float M = Mbuf[0][rq][rl];
  #pragma unroll
  for (int sw = 1; sw < 4; sw++) M = fmaxf(M, Mbuf[sw][rq][rl]);
  float sc[4];
  float lt = 0.f;
  #pragma unroll
  for (int sw = 0; sw < 4; sw++) {
    sc[sw] = EXP2F(Mbuf[sw][rq][rl] - M);
    lt += Lbuf[sw][rq][rl] * sc[sw];
  }
  float inv = 1.f / lt;
  size_t outp = (size_t)(qBase + orow) * DIM + head * DH + c0;
  #pragma unroll
  for (int c = 0; c < 6; c++) {
    float v = 0.f;
    #pragma unroll
    for (int sw = 0; sw < 4; sw++) v += Obuf[sw][orow][c0 + c] * sc[sw];
    v *= inv;
    ushort hi, lo;
    bsplit(v, hi, lo);
    aoH[outp + c] = hi;
    aoL[outp + c] = lo;
  }
}

// ======================= final projection + sigmoid =======================

__global__ __launch_bounds__(256) void out_kernel(const float* __restrict__ h,
    const float* __restrict__ Wout, const float* __restrict__ bout,
    float* __restrict__ out)
{
  int gw = (blockIdx.x * 256 + threadIdx.x) >> 6;
  int lane = threadIdx.x & 63;
  if (gw >= N_NODES) return;
  float s = 0.f;
  #pragma unroll
  for (int c = 0; c < 6; c++)
    s += h[(size_t)gw * DIM + lane + c * 64] * Wout[lane + c * 64];
  #pragma unroll
  for (int off = 32; off >= 1; off >>= 1) s += __shfl_xor(s, off, 64);
  if (lane == 0) out[gw] = 1.f / (1.f + __expf(-(s + bout[0])));
}

// ======================= launch =======================

extern "C" void kernel_launch(void* const* d_in, const int* in_sizes, int n_in,
                              void* d_out, int out_size, void* d_ws, size_t ws_size,
                              hipStream_t stream)
{
  const float* node_emb = (const float*)d_in[0];
  const int*   edge_index = (const int*)d_in[1];
  const float* W_conv = (const float*)d_in[2];
  const float* b_conv = (const float*)d_in[3];
  const float* W_in   = (const float*)d_in[4];
  const float* b_in   = (const float*)d_in[5];
  const float* W_ao   = (const float*)d_in[6];
  const float* b_ao   = (const float*)d_in[7];
  const float* W_out  = (const float*)d_in[8];
  const float* b_out  = (const float*)d_in[9];
  float* out = (float*)d_out;

  const size_t ND = (size_t)N_NODES * DIM;       // 1572864
  const size_t WI = (size_t)QKVD * DIM;          // 442368
  const size_t WC = (size_t)DIM * DIM;           // 147456

  float* h      = (float*)d_ws;
  ushort* aggH  = (ushort*)(h + ND);
  ushort* aggL  = aggH + ND;
  ushort* qhi   = aggL + ND;
  ushort* qlo   = qhi + ND;
  ushort* khi   = qlo + ND;
  ushort* klo   = khi + ND;
  ushort* vthi  = klo + ND;
  ushort* vtlo  = vthi + ND;
  ushort* aoH   = vtlo + ND;
  ushort* aoL   = aoH + ND;
  ushort* wiH   = aoL + ND;
  ushort* wiL   = wiH + WI;
  ushort* waoH  = wiL + WI;
  ushort* waoL  = waoH + WC;
  ushort* wctH  = waoL + WC;
  ushort* wctL  = wctH + 3 * WC;
  ushort* wfH   = wctL + 3 * WC;
  ushort* wfL   = wfH + 3 * WI;
  float* wibc   = (float*)(wfL + 3 * WI);
  int* counts   = (int*)(wibc + 3 * QKVD);
  int* offsets  = counts + N_NODES;
  int* cursor   = offsets + N_NODES + 1;
  int* ssrc     = cursor + N_NODES;

  const int* dst = edge_index;
  const int* src = edge_index + N_EDGES;

  // CSR build
  zero_counts_kernel<<<(N_NODES + 255) / 256, 256, 0, stream>>>(counts, cursor);
  count_kernel<<<N_EDGES / 256, 256, 0, stream>>>(dst, counts);
  scan_kernel<<<1, 1024, 0, stream>>>(counts, offsets);
  scatter_kernel<<<N_EDGES / 256, 256, 0, stream>>>(dst, src, offsets, cursor, ssrc);
  (void)hipMemcpyAsync(h, node_emb, ND * sizeof(float), hipMemcpyDeviceToDevice, stream);

  // weight prep: Wct (transpose+split), Wi/Wao splits, wibc, Wf = Wi@Wct
  transpose_split_kernel<<<dim3(12, 12, 3), dim3(32, 32), 0, stream>>>(W_conv, wctH, wctL);
  split_kernel<<<(int)(WI / 1024), 256, 0, stream>>>(W_in, wiH, wiL, (int)WI);
  split_kernel<<<(int)(WC / 1024), 256, 0, stream>>>(W_ao, waoH, waoL, (int)WC);
  wibc_kernel<<<(3 * QKVD) / 4 / 256 * 256 ? 864 : 864, 256, 0, stream>>>(W_in, b_conv, wibc);
  wprep_gemm<<<dim3(9, 3, 3), 256, 0, stream>>>(wiH, wiL, wctH, wctL, wfH, wfL);

  for (int l = 0; l < N_LAYERS; l++) {
    aggregate_kernel<<<N_NODES, 128, 0, stream>>>(h, ssrc, offsets, aggH, aggL);
    qkv_gemm<<<dim3(9, 32), 256, 0, stream>>>(
        wfH + (size_t)l * WI, wfL + (size_t)l * WI, aggH, aggL,
        wibc + (size_t)l * QKVD, b_in, counts,
        qhi, qlo, khi, klo, vthi, vtlo);
    attn_kernel<<<dim3(8, 128), 256, 0, stream>>>(
        qhi, qlo, khi, klo, vthi, vtlo, aoH, aoL);
    outproj_gemm<<<dim3(32, 3), 256, 0, stream>>>(
        aoH, aoL, waoH, waoL, b_ao, h);
  }
  out_kernel<<<1024, 256, 0, stream>>>(h, W_out, b_out, out);
}